// Round 10
// baseline (644.590 us; speedup 1.0000x reference)
//
#include <hip/hip_runtime.h>
#include <math.h>

#define DIN 640
#define DH 1024
#define DOUT 128
#define CODEDIM 256
#define NE 8
#define NB 8
#define NT 1024
#define NTOK 8192
#define TAU_INV 10.0f
#define FEPS 1e-8f

// out layout: full_output[8*1024*1024], aux[1], div[1], ent[8], mean[8], std[8]
#define AUX_OFF  8388608
#define DIV_OFF  8388609
#define ENT_OFF  8388610
#define MEAN_OFF 8388618
#define STD_OFF  8388626

typedef __bf16 bf16;
typedef bf16 bf16x8 __attribute__((ext_vector_type(8)));
typedef float f32x4 __attribute__((ext_vector_type(4)));

__device__ __forceinline__ float gelu(float x) {
  return 0.5f * x * (1.0f + erff(x * 0.70710678118654752f));
}

// ---------------- block reduction helpers (blockDim multiple of 64) ----------
__device__ __forceinline__ float blk_sum(float v, float* sb) {
  #pragma unroll
  for (int o = 32; o > 0; o >>= 1) v += __shfl_down(v, o, 64);
  __syncthreads();
  if ((threadIdx.x & 63) == 0) sb[threadIdx.x >> 6] = v;
  __syncthreads();
  float tot = 0.f;
  int nw = blockDim.x >> 6;
  for (int i = 0; i < nw; ++i) tot += sb[i];
  return tot;
}

__device__ __forceinline__ float blk_max(float v, float* sb) {
  #pragma unroll
  for (int o = 32; o > 0; o >>= 1) v = fmaxf(v, __shfl_down(v, o, 64));
  __syncthreads();
  if ((threadIdx.x & 63) == 0) sb[threadIdx.x >> 6] = v;
  __syncthreads();
  float m = -3.0e38f;
  int nw = blockDim.x >> 6;
  for (int i = 0; i < nw; ++i) m = fmaxf(m, sb[i]);
  return m;
}

// ---------------- importance softmax + entropy/mean/std ---------------------
__global__ void k_imp(const float* __restrict__ fi, float* __restrict__ imp,
                      float* __restrict__ out) {
  __shared__ float sb[8];
  int e = blockIdx.x, tid = threadIdx.x;
  int d2v = tid + 512;
  float v0 = fi[e*DIN + tid] * 2.0f;          // /temp, temp = 0.5
  float v1 = fi[e*DIN + tid + 256] * 2.0f;
  float v2 = (d2v < DIN) ? fi[e*DIN + d2v] * 2.0f : -3.0e38f;
  float m = blk_max(fmaxf(v0, fmaxf(v1, v2)), sb);
  float e0 = expf(v0 - m), e1 = expf(v1 - m);
  float e2 = (d2v < DIN) ? expf(v2 - m) : 0.f;
  float s = blk_sum(e0 + e1 + e2, sb);
  float inv = 1.0f / s;
  float p0 = e0*inv, p1 = e1*inv, p2 = e2*inv;
  imp[e*DIN + tid] = p0;
  imp[e*DIN + tid + 256] = p1;
  if (d2v < DIN) imp[e*DIN + d2v] = p2;
  float ok2 = (d2v < DIN) ? 1.f : 0.f;
  float sp  = p0 + p1 + ok2*p2;
  float sp2 = p0*p0 + p1*p1 + ok2*p2*p2;
  float se  = p0*logf(p0 + FEPS) + p1*logf(p1 + FEPS) + ok2*p2*logf(p2 + FEPS);
  sp  = blk_sum(sp, sb);
  sp2 = blk_sum(sp2, sb);
  se  = blk_sum(se, sb);
  if (tid == 0) {
    out[ENT_OFF + e]  = -se;
    out[MEAN_OFF + e] = sp * (1.0f/DIN);
    float var = (sp2 - sp*sp*(1.0f/DIN)) * (1.0f/(DIN-1));
    out[STD_OFF + e]  = sqrtf(fmaxf(var, 0.f));
  }
}

// ---------------- anchor normalize + diversity loss --------------------------
__global__ void k_anchor_div(const float* __restrict__ ca, const float* __restrict__ fi,
                             float* __restrict__ anch, float* __restrict__ out) {
  __shared__ float sb[8];
  __shared__ float sd[256];
  int tid = threadIdx.x;
  for (int e = 0; e < NE; ++e) {
    float x = ca[e*CODEDIM + tid];
    float ss = blk_sum(x*x, sb);
    anch[e*CODEDIM + tid] = x / fmaxf(sqrtf(ss), 1e-12f);
  }
  // diversity: sim = fi @ fi^T, off-diag squared sum / 56
  int p = tid >> 2, q = tid & 3;     // pair p in 0..63, quarter q
  int i = p >> 3, j = p & 7;
  float dot = 0.f;
  for (int d = q*160; d < q*160 + 160; ++d) dot += fi[i*DIN + d] * fi[j*DIN + d];
  sd[tid] = dot;
  __syncthreads();
  if (tid < 64) {
    float s = sd[tid*4] + sd[tid*4+1] + sd[tid*4+2] + sd[tid*4+3];
    int ii = tid >> 3, jj = tid & 7;
    float val = (ii != jj) ? s*s : 0.f;
    #pragma unroll
    for (int o = 32; o > 0; o >>= 1) val += __shfl_down(val, o, 64);
    if (tid == 0) out[DIV_OFF] = val * (1.0f/56.0f);
  }
}

// -------- tiled transpose + f32->bf16 (+optional per-src-row scale) ----------
// src[e][R][C] -> dst[e][C][R]; dst[e][c][r] = src[e][r][c] * scale[e][r]
__global__ void k_transpose(const float* __restrict__ src, bf16* __restrict__ dst,
                            int R, int C, const float* __restrict__ scale) {
  __shared__ float tile[64][65];
  int c0 = blockIdx.x*64, r0 = blockIdx.y*64;
  int ee = blockIdx.z;
  const float* s = src + (size_t)ee*R*C;
  bf16* d = dst + (size_t)ee*C*R;
  int tx = threadIdx.x & 63, ty = threadIdx.x >> 6;
  #pragma unroll
  for (int p = 0; p < 16; ++p) {
    int r = p*4 + ty;
    tile[r][tx] = s[(size_t)(r0 + r)*C + c0 + tx];
  }
  __syncthreads();
  float sc = scale ? scale[(size_t)ee*R + r0 + tx] : 1.0f;
  #pragma unroll
  for (int p = 0; p < 16; ++p) {
    int cr = p*4 + ty;
    d[(size_t)(c0 + cr)*R + r0 + tx] = (bf16)(tile[tx][cr] * sc);
  }
}

// ---------------- h f32 -> bf16 (row-major, shared across experts) -----------
__global__ void k_h2b(const float* __restrict__ h, bf16* __restrict__ xb) {
  size_t i = (size_t)blockIdx.x*256 + threadIdx.x;   // 8 elements per thread
  const float4* p = (const float4*)(h + i*8);
  float4 v0 = p[0], v1 = p[1];
  bf16x8 o;
  o[0]=(bf16)v0.x; o[1]=(bf16)v0.y; o[2]=(bf16)v0.z; o[3]=(bf16)v0.w;
  o[4]=(bf16)v1.x; o[5]=(bf16)v1.y; o[6]=(bf16)v1.z; o[7]=(bf16)v1.w;
  *(bf16x8*)(xb + i*8) = o;
}

// ---------------- router: cosine logits + gumbel softmax ---------------------
__global__ void k_router(const float* __restrict__ ce, const float* __restrict__ gn,
                         const float* __restrict__ anch, float* __restrict__ ew) {
  __shared__ float anc[NE*CODEDIM];
  int tid = threadIdx.x;
  for (int i2 = tid; i2 < NE*CODEDIM; i2 += 256) anc[i2] = anch[i2];
  __syncthreads();
  int wv = tid >> 6, lane = tid & 63;
  int token = blockIdx.x*4 + wv;
  float4 x = *(const float4*)(ce + (size_t)token*CODEDIM + lane*4);
  float ss = x.x*x.x + x.y*x.y + x.z*x.z + x.w*x.w;
  #pragma unroll
  for (int o = 1; o < 64; o <<= 1) ss += __shfl_xor(ss, o, 64);
  float inv = 1.0f / fmaxf(sqrtf(ss), 1e-12f);
  const float* g = gn + (size_t)token*NE;
  float z[8];
  float m = -3.0e38f;
  #pragma unroll
  for (int e2 = 0; e2 < NE; ++e2) {
    const float* a = anc + e2*CODEDIM + lane*4;
    float d = x.x*a[0] + x.y*a[1] + x.z*a[2] + x.w*a[3];
    #pragma unroll
    for (int o = 1; o < 64; o <<= 1) d += __shfl_xor(d, o, 64);
    z[e2] = (d*inv + g[e2]) * TAU_INV;
    m = fmaxf(m, z[e2]);
  }
  float ssum = 0.f;
  float pz[8];
  #pragma unroll
  for (int e2 = 0; e2 < NE; ++e2) { pz[e2] = expf(z[e2] - m); ssum += pz[e2]; }
  float num = 0.f;
  #pragma unroll
  for (int e2 = 0; e2 < NE; ++e2) num = (lane == e2) ? pz[e2] : num;  // static idx
  if (lane < NE) ew[(size_t)token*NE + lane] = num / ssum;
}

// ================== GEMM1: H = gelu(X @ W1 + b1), bf16 out ===================
// Runs per 4-expert HALF (ebase=0,4): H buffer is [4][NTOK][DH] bf16 = 64MB
// (r9 bug: full [8] H is 128MB but only 16.7MB was allocated -> clobbered ew).
// Tile 64(M)x256(N), BK=32, 4 waves each 64x64 = 4x4 of 16x16x32 MFMA;
// 8 ds_read_b128 per 16 MFMA = 0.5KB/MFMA. Reg-staged dbuf, 72B padded
// stride (conflict-free). bid&3 -> expert keeps expert<->XCD affinity.
#define G1_AS 4608      // 64*72
#define G1_BS 18432     // 256*72
__global__ __launch_bounds__(256, 3)
void k_g1(const bf16* __restrict__ xb, const bf16* __restrict__ w1t,
          const float* __restrict__ b1, bf16* __restrict__ Hb, int ebase) {
  __shared__ __align__(16) char L[2*G1_AS + 2*G1_BS];   // 46080 B
  const int bid = blockIdx.x;
  const int el = bid & 3, e = ebase + el;
  const int q = bid >> 2;
  const int nt = q & 3, mt = q >> 2;
  const int M0 = mt * 64, N0 = nt * 256;
  const int tid = threadIdx.x;
  const int lane = tid & 63, w = tid >> 6;
  const int l15 = lane & 15, g4 = lane >> 4;
  const int arow = tid >> 2, aslot = tid & 3;
  const char* gA = (const char*)xb + (size_t)(M0 + arow)*(DIN*2) + aslot*16;
  const unsigned ldsA = (unsigned)(arow*72 + aslot*16);
  const char* gBb = (const char*)w1t + (size_t)(e*DH + N0)*(DIN*2);

  f32x4 acc[4][4] = {};
  bf16x8 ra, rb[4];

  auto LOADR = [&](int t) {
    size_t ko = (size_t)t * 64;          // 32 elems * 2B
    ra = *(const bf16x8*)(gA + ko);
    #pragma unroll
    for (int j = 0; j < 4; ++j) {
      int c = j*256 + tid;
      int row = c >> 2, slot = c & 3;    // 256 rows x 4 slots
      rb[j] = *(const bf16x8*)(gBb + (size_t)row*(DIN*2) + ko + slot*16);
    }
  };
  auto WRITEL = [&](int buf) {
    *(bf16x8*)(L + buf*G1_AS + ldsA) = ra;
    char* Bb = L + 2*G1_AS + buf*G1_BS;
    #pragma unroll
    for (int j = 0; j < 4; ++j) {
      int c = j*256 + tid;
      int row = c >> 2, slot = c & 3;
      *(bf16x8*)(Bb + row*72 + slot*16) = rb[j];
    }
  };

  LOADR(0); WRITEL(0); __syncthreads();
  for (int t = 0; t < 20; ++t) {
    int cur = t & 1;
    if (t < 19) LOADR(t + 1);            // issue-early (T14): hides under MFMA
    const char* Ab = L + cur*G1_AS;
    const char* Bb = L + 2*G1_AS + cur*G1_BS;
    bf16x8 af[4], bfr[4];
    #pragma unroll
    for (int mi = 0; mi < 4; ++mi)
      af[mi] = *(const bf16x8*)(Ab + (mi*16 + l15)*72 + g4*16);
    #pragma unroll
    for (int ni = 0; ni < 4; ++ni)
      bfr[ni] = *(const bf16x8*)(Bb + (w*64 + ni*16 + l15)*72 + g4*16);
    #pragma unroll
    for (int mi = 0; mi < 4; ++mi)
      #pragma unroll
      for (int ni = 0; ni < 4; ++ni)
        acc[mi][ni] = __builtin_amdgcn_mfma_f32_16x16x32_bf16(
            af[mi], bfr[ni], acc[mi][ni], 0, 0, 0);
    if (t < 19) { WRITEL(cur ^ 1); __syncthreads(); }
  }
  __syncthreads();       // Hs (below) overlays the A/B buffers
  // epilogue: +b1, exact GELU -> LDS (padded 520B rows) -> coalesced bf16 out
  float b1v[4];
  #pragma unroll
  for (int ni = 0; ni < 4; ++ni)
    b1v[ni] = b1[e*DH + N0 + w*64 + ni*16 + l15];
  #pragma unroll
  for (int mi = 0; mi < 4; ++mi)
    #pragma unroll
    for (int ni = 0; ni < 4; ++ni)
      #pragma unroll
      for (int r = 0; r < 4; ++r) {
        float v = gelu(acc[mi][ni][r] + b1v[ni]);   // C/D: row=(l>>4)*4+r, col=l&15
        int row = mi*16 + g4*4 + r;
        int col = w*64 + ni*16 + l15;
        *(bf16*)(L + row*520 + col*2) = (bf16)v;
      }
  __syncthreads();
  #pragma unroll
  for (int j = 0; j < 8; ++j) {
    int c = j*256 + tid;
    int row = c >> 5, slot = c & 31;     // 64 rows x 32 slots of 16B
    bf16x8 v = *(const bf16x8*)(L + row*520 + slot*16);
    *(bf16x8*)((char*)Hb + (size_t)(el*NTOK + M0 + row)*(DH*2) + (size_t)N0*2 + slot*16) = v;
  }
}

// ================== GEMM2: out = (H @ W2 + b2) * gate, f32 ===================
// Per 4-expert half. Tile 64(M)x128(N=DOUT), BK=32, K=1024; 4 waves each
// 64x32 = 4x2 subtiles. Same reg-staged dbuf + 72B padded stride.
__global__ __launch_bounds__(256, 4)
void k_g2(const bf16* __restrict__ Hb, const bf16* __restrict__ w2t,
          const float* __restrict__ b2, const float* __restrict__ ew,
          float* __restrict__ out, int ebase) {
  __shared__ __align__(16) char L[2*4608 + 2*9216];    // A dbuf + B dbuf
  const int bid = blockIdx.x;
  const int el = bid & 3, e = ebase + el;
  const int mt = bid >> 2;
  const int M0 = mt * 64;
  const int tid = threadIdx.x;
  const int lane = tid & 63, w = tid >> 6;
  const int l15 = lane & 15, g4 = lane >> 4;
  const int arow = tid >> 2, aslot = tid & 3;
  const char* gA = (const char*)Hb + (size_t)(el*NTOK + M0 + arow)*(DH*2) + aslot*16;
  const unsigned ldsA = (unsigned)(arow*72 + aslot*16);
  const char* gBb = (const char*)w2t + (size_t)(e*DOUT)*(DH*2);

  f32x4 acc[4][2] = {};
  bf16x8 ra, rb[2];

  auto LOADR = [&](int t) {
    size_t ko = (size_t)t * 64;
    ra = *(const bf16x8*)(gA + ko);
    #pragma unroll
    for (int j = 0; j < 2; ++j) {
      int c = j*256 + tid;
      int row = c >> 2, slot = c & 3;    // 128 rows x 4 slots
      rb[j] = *(const bf16x8*)(gBb + (size_t)row*(DH*2) + ko + slot*16);
    }
  };
  auto WRITEL = [&](int buf) {
    *(bf16x8*)(L + buf*4608 + ldsA) = ra;
    char* Bb = L + 2*4608 + buf*9216;
    #pragma unroll
    for (int j = 0; j < 2; ++j) {
      int c = j*256 + tid;
      int row = c >> 2, slot = c & 3;
      *(bf16x8*)(Bb + row*72 + slot*16) = rb[j];
    }
  };

  LOADR(0); WRITEL(0); __syncthreads();
  for (int t = 0; t < 32; ++t) {
    int cur = t & 1;
    if (t < 31) LOADR(t + 1);
    const char* Ab = L + cur*4608;
    const char* Bb = L + 2*4608 + cur*9216;
    bf16x8 af[4], bfr[2];
    #pragma unroll
    for (int mi = 0; mi < 4; ++mi)
      af[mi] = *(const bf16x8*)(Ab + (mi*16 + l15)*72 + g4*16);
    #pragma unroll
    for (int ni = 0; ni < 2; ++ni)
      bfr[ni] = *(const bf16x8*)(Bb + (w*32 + ni*16 + l15)*72 + g4*16);
    #pragma unroll
    for (int mi = 0; mi < 4; ++mi)
      #pragma unroll
      for (int ni = 0; ni < 2; ++ni)
        acc[mi][ni] = __builtin_amdgcn_mfma_f32_16x16x32_bf16(
            af[mi], bfr[ni], acc[mi][ni], 0, 0, 0);
    if (t < 31) { WRITEL(cur ^ 1); __syncthreads(); }
  }
  // epilogue: +b2, *gate, direct f32 stores (16-lane groups -> 64B segments)
  float b2v[2];
  #pragma unroll
  for (int ni = 0; ni < 2; ++ni)
    b2v[ni] = b2[e*DOUT + w*32 + ni*16 + l15];
  float gt[4][4];
  #pragma unroll
  for (int mi = 0; mi < 4; ++mi)
    #pragma unroll
    for (int r = 0; r < 4; ++r)
      gt[mi][r] = ew[(size_t)(M0 + mi*16 + g4*4 + r)*NE + e];
  #pragma unroll
  for (int mi = 0; mi < 4; ++mi)
    #pragma unroll
    for (int ni = 0; ni < 2; ++ni)
      #pragma unroll
      for (int r = 0; r < 4; ++r) {
        int tok = M0 + mi*16 + g4*4 + r;
        int o = w*32 + ni*16 + l15;
        out[(size_t)tok*(NE*DOUT) + e*DOUT + o] = (acc[mi][ni][r] + b2v[ni]) * gt[mi][r];
      }
}

// ---------------- expert counts + partial sums --------------------------------
__global__ void k_counts(const float* __restrict__ ew, float* __restrict__ counts,
                         float* __restrict__ partials) {
  __shared__ float sb[4];
  int g2 = blockIdx.x*256 + threadIdx.x;   // (t,e) flat, 0..8191
  float c = 0.f;
  #pragma unroll
  for (int b = 0; b < NB; ++b) c += ew[b*(NT*NE) + g2];
  counts[g2] = c;
  float tot = blk_sum(c, sb);
  if (threadIdx.x == 0) partials[blockIdx.x] = tot;
}

// ---------------- aux loss ----------------------------------------------------
__global__ void k_aux(const float* __restrict__ counts, const float* __restrict__ partials,
                      float* __restrict__ out) {
  __shared__ float sb[4];
  int tid = threadIdx.x;
  float pv = (tid < 32) ? partials[tid] : 0.f;
  float total = blk_sum(pv, sb);
  float invt = 1.0f / (total + FEPS);
  float sq = 0.f, ent = 0.f;
  for (int i2 = tid; i2 < NT*NE; i2 += 256) {
    float c = counts[i2];
    sq += c*c;
    float ld = c * invt;
    ent -= ld * logf(ld + FEPS);
  }
  sq = blk_sum(sq, sb);
  ent = blk_sum(ent, sb);
  if (tid == 0) {
    float var = (sq - total*total*(1.0f/(NT*NE))) * (1.0f/(NT*NE - 1));
    float stdv = sqrtf(fmaxf(var, 0.f));
    float ment = 0.f;
    #pragma unroll
    for (int e2 = 0; e2 < NE; ++e2) ment += out[ENT_OFF + e2];
    ment *= (1.0f/NE);
    out[AUX_OFF] = 0.5f*(stdv + ent) + 0.01f*ment;
  }
}

// ---------------- launch ------------------------------------------------------
extern "C" void kernel_launch(void* const* d_in, const int* in_sizes, int n_in,
                              void* d_out, int out_size, void* d_ws, size_t ws_size,
                              hipStream_t stream) {
  const float* h  = (const float*)d_in[0];
  const float* ce = (const float*)d_in[1];
  const float* gn = (const float*)d_in[2];
  const float* ca = (const float*)d_in[3];
  const float* fi = (const float*)d_in[4];
  const float* W1 = (const float*)d_in[5];
  const float* b1 = (const float*)d_in[6];
  const float* W2 = (const float*)d_in[7];
  const float* b2 = (const float*)d_in[8];
  float* out = (float*)d_out;
  char* ws = (char*)d_ws;
  // ws layout (bytes) — total 90,505,216 (Hbuf = [4][8192][1024] bf16 = 64MB)
  bf16*  w1t      = (bf16*)(ws);                 // [E][DH][DIN] bf16 (imp-folded): 10,485,760
  bf16*  w2t      = (bf16*)(ws + 10485760);      // [E][DOUT][DH] bf16: 2,097,152
  bf16*  xbuf     = (bf16*)(ws + 12582912);      // [8192][640] bf16: 10,485,760
  float* imp      = (float*)(ws + 23068672);     // [E][DIN]: 20,480
  float* anch     = (float*)(ws + 23089152);     // [E][CODE]: 8,192
  float* ew       = (float*)(ws + 23097344);     // [B][T][E]: 262,144
  float* counts   = (float*)(ws + 23359488);     // [T*E]: 32,768
  float* partials = (float*)(ws + 23392256);     // [32]: 128
  bf16*  Hbuf     = (bf16*)(ws + 23396352);      // [4][8192][1024] bf16: 67,108,864

  k_imp<<<dim3(8), dim3(256), 0, stream>>>(fi, imp, out);
  k_anchor_div<<<dim3(1), dim3(256), 0, stream>>>(ca, fi, anch, out);
  k_transpose<<<dim3(16, 10, 8), dim3(256), 0, stream>>>(W1, w1t, 640, 1024, imp);
  k_transpose<<<dim3(2, 16, 8), dim3(256), 0, stream>>>(W2, w2t, 1024, 128, nullptr);
  k_h2b<<<dim3(2560), dim3(256), 0, stream>>>(h, xbuf);
  k_router<<<dim3(2048), dim3(256), 0, stream>>>(ce, gn, anch, ew);
  k_g1<<<dim3(2048), dim3(256), 0, stream>>>(xbuf, w1t, b1, Hbuf, 0);
  k_g2<<<dim3(512), dim3(256), 0, stream>>>(Hbuf, w2t, b2, ew, out, 0);
  k_g1<<<dim3(2048), dim3(256), 0, stream>>>(xbuf, w1t, b1, Hbuf, 4);
  k_g2<<<dim3(512), dim3(256), 0, stream>>>(Hbuf, w2t, b2, ew, out, 4);
  k_counts<<<dim3(32), dim3(256), 0, stream>>>(ew, counts, partials);
  k_aux<<<dim3(1), dim3(256), 0, stream>>>(counts, partials, out);
}

// Round 11
// 234.303 us; speedup vs baseline: 2.7511x; 2.7511x over previous
//
#include <hip/hip_runtime.h>
#include <math.h>

#define DIN 640
#define DH 1024
#define DOUT 128
#define CODEDIM 256
#define NE 8
#define NB 8
#define NT 1024
#define NTOK 8192
#define TAU_INV 10.0f
#define FEPS 1e-8f

// out layout: full_output[8*1024*1024], aux[1], div[1], ent[8], mean[8], std[8]
#define AUX_OFF  8388608
#define DIV_OFF  8388609
#define ENT_OFF  8388610
#define MEAN_OFF 8388618
#define STD_OFF  8388626

typedef __bf16 bf16;
typedef bf16 bf16x8 __attribute__((ext_vector_type(8)));
typedef float f32x4 __attribute__((ext_vector_type(4)));

__device__ __forceinline__ float gelu(float x) {
  return 0.5f * x * (1.0f + erff(x * 0.70710678118654752f));
}

#define BAR() do { asm volatile("" ::: "memory"); __builtin_amdgcn_s_barrier(); asm volatile("" ::: "memory"); } while(0)
#define VMCNT5 asm volatile("s_waitcnt vmcnt(5)" ::: "memory")
#define VMCNT6 asm volatile("s_waitcnt vmcnt(6)" ::: "memory")
#define VMCNT0 asm volatile("s_waitcnt vmcnt(0)" ::: "memory")

// async global->LDS, 16B/lane; LDS dest is wave-uniform base (HW adds lane*16);
// global source IS per-lane (pre-swizzled-global pattern, r5-proven).
__device__ __forceinline__ void gload16(const void* g, void* l) {
  __builtin_amdgcn_global_load_lds(
      (const __attribute__((address_space(1))) unsigned int*)g,
      (__attribute__((address_space(3))) unsigned int*)l, 16, 0, 0);
}

// ---------------- block reduction helpers (blockDim multiple of 64) ----------
__device__ __forceinline__ float blk_sum(float v, float* sb) {
  #pragma unroll
  for (int o = 32; o > 0; o >>= 1) v += __shfl_down(v, o, 64);
  __syncthreads();
  if ((threadIdx.x & 63) == 0) sb[threadIdx.x >> 6] = v;
  __syncthreads();
  float tot = 0.f;
  int nw = blockDim.x >> 6;
  for (int i = 0; i < nw; ++i) tot += sb[i];
  return tot;
}

__device__ __forceinline__ float blk_max(float v, float* sb) {
  #pragma unroll
  for (int o = 32; o > 0; o >>= 1) v = fmaxf(v, __shfl_down(v, o, 64));
  __syncthreads();
  if ((threadIdx.x & 63) == 0) sb[threadIdx.x >> 6] = v;
  __syncthreads();
  float m = -3.0e38f;
  int nw = blockDim.x >> 6;
  for (int i = 0; i < nw; ++i) m = fmaxf(m, sb[i]);
  return m;
}

// ---------------- importance softmax + entropy/mean/std ---------------------
__global__ void k_imp(const float* __restrict__ fi, float* __restrict__ imp,
                      float* __restrict__ out) {
  __shared__ float sb[8];
  int e = blockIdx.x, tid = threadIdx.x;
  int d2v = tid + 512;
  float v0 = fi[e*DIN + tid] * 2.0f;          // /temp, temp = 0.5
  float v1 = fi[e*DIN + tid + 256] * 2.0f;
  float v2 = (d2v < DIN) ? fi[e*DIN + d2v] * 2.0f : -3.0e38f;
  float m = blk_max(fmaxf(v0, fmaxf(v1, v2)), sb);
  float e0 = expf(v0 - m), e1 = expf(v1 - m);
  float e2 = (d2v < DIN) ? expf(v2 - m) : 0.f;
  float s = blk_sum(e0 + e1 + e2, sb);
  float inv = 1.0f / s;
  float p0 = e0*inv, p1 = e1*inv, p2 = e2*inv;
  imp[e*DIN + tid] = p0;
  imp[e*DIN + tid + 256] = p1;
  if (d2v < DIN) imp[e*DIN + d2v] = p2;
  float ok2 = (d2v < DIN) ? 1.f : 0.f;
  float sp  = p0 + p1 + ok2*p2;
  float sp2 = p0*p0 + p1*p1 + ok2*p2*p2;
  float se  = p0*logf(p0 + FEPS) + p1*logf(p1 + FEPS) + ok2*p2*logf(p2 + FEPS);
  sp  = blk_sum(sp, sb);
  sp2 = blk_sum(sp2, sb);
  se  = blk_sum(se, sb);
  if (tid == 0) {
    out[ENT_OFF + e]  = -se;
    out[MEAN_OFF + e] = sp * (1.0f/DIN);
    float var = (sp2 - sp*sp*(1.0f/DIN)) * (1.0f/(DIN-1));
    out[STD_OFF + e]  = sqrtf(fmaxf(var, 0.f));
  }
}

// ---------------- anchor normalize + diversity loss --------------------------
__global__ void k_anchor_div(const float* __restrict__ ca, const float* __restrict__ fi,
                             float* __restrict__ anch, float* __restrict__ out) {
  __shared__ float sb[8];
  __shared__ float sd[256];
  int tid = threadIdx.x;
  for (int e = 0; e < NE; ++e) {
    float x = ca[e*CODEDIM + tid];
    float ss = blk_sum(x*x, sb);
    anch[e*CODEDIM + tid] = x / fmaxf(sqrtf(ss), 1e-12f);
  }
  // diversity: sim = fi @ fi^T, off-diag squared sum / 56
  int p = tid >> 2, q = tid & 3;     // pair p in 0..63, quarter q
  int i = p >> 3, j = p & 7;
  float dot = 0.f;
  for (int d = q*160; d < q*160 + 160; ++d) dot += fi[i*DIN + d] * fi[j*DIN + d];
  sd[tid] = dot;
  __syncthreads();
  if (tid < 64) {
    float s = sd[tid*4] + sd[tid*4+1] + sd[tid*4+2] + sd[tid*4+3];
    int ii = tid >> 3, jj = tid & 7;
    float val = (ii != jj) ? s*s : 0.f;
    #pragma unroll
    for (int o = 32; o > 0; o >>= 1) val += __shfl_down(val, o, 64);
    if (tid == 0) out[DIV_OFF] = val * (1.0f/56.0f);
  }
}

// -------- tiled transpose + f32->bf16 (+optional per-src-row scale) ----------
// src[e][R][C] -> dst[e][C][R]; dst[e][c][r] = src[e][r][c] * scale[e][r]
__global__ void k_transpose(const float* __restrict__ src, bf16* __restrict__ dst,
                            int R, int C, const float* __restrict__ scale) {
  __shared__ float tile[64][65];
  int c0 = blockIdx.x*64, r0 = blockIdx.y*64;
  int ee = blockIdx.z;
  const float* s = src + (size_t)ee*R*C;
  bf16* d = dst + (size_t)ee*C*R;
  int tx = threadIdx.x & 63, ty = threadIdx.x >> 6;
  #pragma unroll
  for (int p = 0; p < 16; ++p) {
    int r = p*4 + ty;
    tile[r][tx] = s[(size_t)(r0 + r)*C + c0 + tx];
  }
  __syncthreads();
  float sc = scale ? scale[(size_t)ee*R + r0 + tx] : 1.0f;
  #pragma unroll
  for (int p = 0; p < 16; ++p) {
    int cr = p*4 + ty;
    d[(size_t)(c0 + cr)*R + r0 + tx] = (bf16)(tile[tx][cr] * sc);
  }
}

// ---------------- h f32 -> bf16 (row-major, shared across experts) -----------
__global__ void k_h2b(const float* __restrict__ h, bf16* __restrict__ xb) {
  size_t i = (size_t)blockIdx.x*256 + threadIdx.x;   // 8 elements per thread
  const float4* p = (const float4*)(h + i*8);
  float4 v0 = p[0], v1 = p[1];
  bf16x8 o;
  o[0]=(bf16)v0.x; o[1]=(bf16)v0.y; o[2]=(bf16)v0.z; o[3]=(bf16)v0.w;
  o[4]=(bf16)v1.x; o[5]=(bf16)v1.y; o[6]=(bf16)v1.z; o[7]=(bf16)v1.w;
  *(bf16x8*)(xb + i*8) = o;
}

// ---------------- router: cosine logits + gumbel softmax ---------------------
__global__ void k_router(const float* __restrict__ ce, const float* __restrict__ gn,
                         const float* __restrict__ anch, float* __restrict__ ew) {
  __shared__ float anc[NE*CODEDIM];
  int tid = threadIdx.x;
  for (int i2 = tid; i2 < NE*CODEDIM; i2 += 256) anc[i2] = anch[i2];
  __syncthreads();
  int wv = tid >> 6, lane = tid & 63;
  int token = blockIdx.x*4 + wv;
  float4 x = *(const float4*)(ce + (size_t)token*CODEDIM + lane*4);
  float ss = x.x*x.x + x.y*x.y + x.z*x.z + x.w*x.w;
  #pragma unroll
  for (int o = 1; o < 64; o <<= 1) ss += __shfl_xor(ss, o, 64);
  float inv = 1.0f / fmaxf(sqrtf(ss), 1e-12f);
  const float* g = gn + (size_t)token*NE;
  float z[8];
  float m = -3.0e38f;
  #pragma unroll
  for (int e2 = 0; e2 < NE; ++e2) {
    const float* a = anc + e2*CODEDIM + lane*4;
    float d = x.x*a[0] + x.y*a[1] + x.z*a[2] + x.w*a[3];
    #pragma unroll
    for (int o = 1; o < 64; o <<= 1) d += __shfl_xor(d, o, 64);
    z[e2] = (d*inv + g[e2]) * TAU_INV;
    m = fmaxf(m, z[e2]);
  }
  float ssum = 0.f;
  float pz[8];
  #pragma unroll
  for (int e2 = 0; e2 < NE; ++e2) { pz[e2] = expf(z[e2] - m); ssum += pz[e2]; }
  float num = 0.f;
  #pragma unroll
  for (int e2 = 0; e2 < NE; ++e2) num = (lane == e2) ? pz[e2] : num;  // static idx
  if (lane < NE) ew[(size_t)token*NE + lane] = num / ssum;
}

// ================== GEMM1: H = gelu(X @ W1 + b1), bf16 out ===================
// global_load_lds dbuf (r5-proven machinery) + 16x16x32 MFMA 4x4 acc
// (0.5KB LDS per MFMA, LDS ~= MFMA cycles). Tile 64(M)x256(N), BK=32, 20 steps,
// 4 waves each own 64x64. LDS: A dbuf 2x4KB + B dbuf 2x16KB = 40KB.
// Rows are 64B; XOR swizzle on the two 16B-slot bits from row bits 1-2:
// phys = a ^ (((a>>7)&3)<<4). 16-lane fragment rows -> 8 bank-slots x2 = 2-way
// aliasing = FREE (m136). Staged via inverse-swizzled per-lane GLOBAL source +
// linear LDS dest (T21). Counted vmcnt(5) = own wave's 5 in-flight loads.
__global__ __launch_bounds__(256, 3)
void k_g1(const bf16* __restrict__ xb, const bf16* __restrict__ w1t,
          const float* __restrict__ b1, bf16* __restrict__ Hb, int ebase) {
  __shared__ __align__(16) char L[40960];
  const int bid = blockIdx.x;
  const int el = bid & 3, e = ebase + el;      // bid&7 -> XCD: expert pinned to 2 XCDs
  const int nt = (bid >> 2) & 3, mt = bid >> 4;
  const int M0 = mt * 64, N0 = nt * 256;
  const int tid = threadIdx.x;
  const int lane = tid & 63, w = tid >> 6;
  const int l15 = lane & 15, g4 = lane >> 4;
  const int nb = w * 64;                        // wave's N-chunk

  // staging sources (per-lane, inverse-swizzled; involution on bits 4-5)
  unsigned pA = (unsigned)(w*1024 + lane*16);
  unsigned qA = pA ^ (((pA >> 7) & 3u) << 4);
  const char* gAsrc = (const char*)xb + (size_t)(M0 + (int)(qA >> 6))*(DIN*2) + (qA & 63u);
  const char* gBsrc[4];
  #pragma unroll
  for (int j = 0; j < 4; ++j) {
    unsigned p = (unsigned)((w*4 + j)*1024 + lane*16);
    unsigned q = p ^ (((p >> 7) & 3u) << 4);
    gBsrc[j] = (const char*)w1t + (size_t)(e*DH + N0 + (int)(q >> 6))*(DIN*2) + (q & 63u);
  }
  auto STAGE = [&](int buf, int t) {
    size_t ko = (size_t)t * 64;
    gload16(gAsrc + ko, L + buf*4096 + w*1024);
    #pragma unroll
    for (int j = 0; j < 4; ++j)
      gload16(gBsrc[j] + ko, L + 8192 + buf*16384 + (w*4 + j)*1024);
  };

  // swizzled read offsets (16-lane rows -> 2-way = free)
  unsigned afOff[4], bfOff[4];
  #pragma unroll
  for (int mi = 0; mi < 4; ++mi) {
    int row = mi*16 + l15;
    afOff[mi] = (unsigned)(row*64 + ((g4 ^ ((row >> 1) & 3)) << 4));
  }
  #pragma unroll
  for (int ni = 0; ni < 4; ++ni) {
    int row = nb + ni*16 + l15;
    bfOff[ni] = (unsigned)(row*64 + ((g4 ^ ((row >> 1) & 3)) << 4));
  }

  f32x4 acc[4][4] = {};
  STAGE(0, 0);
  for (int t = 0; t < 20; ++t) {
    int buf = t & 1;
    if (t < 19) { STAGE(buf ^ 1, t + 1); VMCNT5; } else { VMCNT0; }
    BAR();
    const char* Ab = L + buf*4096;
    const char* Bb = L + 8192 + buf*16384;
    bf16x8 af[4], bfr[4];
    #pragma unroll
    for (int mi = 0; mi < 4; ++mi) af[mi] = *(const bf16x8*)(Ab + afOff[mi]);
    #pragma unroll
    for (int ni = 0; ni < 4; ++ni) bfr[ni] = *(const bf16x8*)(Bb + bfOff[ni]);
    #pragma unroll
    for (int mi = 0; mi < 4; ++mi)
      #pragma unroll
      for (int ni = 0; ni < 4; ++ni)
        acc[mi][ni] = __builtin_amdgcn_mfma_f32_16x16x32_bf16(
            af[mi], bfr[ni], acc[mi][ni], 0, 0, 0);
    BAR();
  }
  __syncthreads();
  // epilogue: +b1, exact GELU -> LDS overlay (520B rows) -> coalesced bf16 out
  float b1v[4];
  #pragma unroll
  for (int ni = 0; ni < 4; ++ni)
    b1v[ni] = b1[e*DH + N0 + nb + ni*16 + l15];
  #pragma unroll
  for (int mi = 0; mi < 4; ++mi)
    #pragma unroll
    for (int ni = 0; ni < 4; ++ni)
      #pragma unroll
      for (int r = 0; r < 4; ++r) {
        float v = gelu(acc[mi][ni][r] + b1v[ni]);   // C/D: row=(l>>4)*4+r, col=l&15
        int row = mi*16 + g4*4 + r;
        int col = nb + ni*16 + l15;
        *(bf16*)(L + row*520 + col*2) = (bf16)v;
      }
  __syncthreads();
  #pragma unroll
  for (int j = 0; j < 8; ++j) {
    int c = j*256 + tid;
    int row = c >> 5, slot = c & 31;     // 64 rows x 32 slots of 16B
    bf16x8 v = *(const bf16x8*)(L + row*520 + slot*16);
    *(bf16x8*)((char*)Hb + (size_t)(el*NTOK + M0 + row)*(DH*2) + (size_t)N0*2 + slot*16) = v;
  }
}

// ================== GEMM2: out = (H @ W2 + b2) * gate, f32 ===================
// Same machinery. Tile 64(M)x128(N=DOUT), BK=64 (128B rows), 16 steps; 4 waves
// each 64x32 (acc 4x2). Swizzle: phys = a ^ (((a>>7)&7)<<4) (classic G4 fix).
// LDS: A dbuf 2x8KB + B dbuf 2x16KB = 48KB. 6 gload/wave/step -> vmcnt(6).
__global__ __launch_bounds__(256, 3)
void k_g2(const bf16* __restrict__ Hb, const bf16* __restrict__ w2t,
          const float* __restrict__ b2, const float* __restrict__ ew,
          float* __restrict__ out, int ebase) {
  __shared__ __align__(16) char L[49152];
  const int bid = blockIdx.x;
  const int el = bid & 3, e = ebase + el;
  const int mt = bid >> 2;
  const int M0 = mt * 64;
  const int tid = threadIdx.x;
  const int lane = tid & 63, w = tid >> 6;
  const int l15 = lane & 15, g4 = lane >> 4;
  const int nb = w * 32;

  const char* gAsrc[2];
  #pragma unroll
  for (int j = 0; j < 2; ++j) {
    unsigned p = (unsigned)((w*2 + j)*1024 + lane*16);
    unsigned q = p ^ (((p >> 7) & 7u) << 4);
    gAsrc[j] = (const char*)Hb + (size_t)(el*NTOK + M0 + (int)(q >> 7))*(DH*2) + (q & 127u);
  }
  const char* gBsrc[4];
  #pragma unroll
  for (int j = 0; j < 4; ++j) {
    unsigned p = (unsigned)((w*4 + j)*1024 + lane*16);
    unsigned q = p ^ (((p >> 7) & 7u) << 4);
    gBsrc[j] = (const char*)w2t + (size_t)(e*DOUT + (int)(q >> 7))*(DH*2) + (q & 127u);
  }
  auto STAGE = [&](int buf, int t) {
    size_t ko = (size_t)t * 128;
    #pragma unroll
    for (int j = 0; j < 2; ++j)
      gload16(gAsrc[j] + ko, L + buf*8192 + (w*2 + j)*1024);
    #pragma unroll
    for (int j = 0; j < 4; ++j)
      gload16(gBsrc[j] + ko, L + 16384 + buf*16384 + (w*4 + j)*1024);
  };

  unsigned afOff[4][2], bfOff[2][2];
  #pragma unroll
  for (int mi = 0; mi < 4; ++mi)
    #pragma unroll
    for (int kk = 0; kk < 2; ++kk) {
      int row = mi*16 + l15;
      int slot = kk*4 + g4;
      afOff[mi][kk] = (unsigned)(row*128 + ((slot ^ (row & 7)) << 4));
    }
  #pragma unroll
  for (int ni = 0; ni < 2; ++ni)
    #pragma unroll
    for (int kk = 0; kk < 2; ++kk) {
      int row = nb + ni*16 + l15;
      int slot = kk*4 + g4;
      bfOff[ni][kk] = (unsigned)(row*128 + ((slot ^ (row & 7)) << 4));
    }

  f32x4 acc[4][2] = {};
  STAGE(0, 0);
  for (int t = 0; t < 16; ++t) {
    int buf = t & 1;
    if (t < 15) { STAGE(buf ^ 1, t + 1); VMCNT6; } else { VMCNT0; }
    BAR();
    const char* Ab = L + buf*8192;
    const char* Bb = L + 16384 + buf*16384;
    #pragma unroll
    for (int kk = 0; kk < 2; ++kk) {
      bf16x8 af[4], bfr[2];
      #pragma unroll
      for (int mi = 0; mi < 4; ++mi) af[mi] = *(const bf16x8*)(Ab + afOff[mi][kk]);
      #pragma unroll
      for (int ni = 0; ni < 2; ++ni) bfr[ni] = *(const bf16x8*)(Bb + bfOff[ni][kk]);
      #pragma unroll
      for (int mi = 0; mi < 4; ++mi)
        #pragma unroll
        for (int ni = 0; ni < 2; ++ni)
          acc[mi][ni] = __builtin_amdgcn_mfma_f32_16x16x32_bf16(
              af[mi], bfr[ni], acc[mi][ni], 0, 0, 0);
    }
    BAR();
  }
  // epilogue: +b2, *gate, direct f32 stores (16-lane groups -> 64B segments)
  float b2v[2];
  #pragma unroll
  for (int ni = 0; ni < 2; ++ni)
    b2v[ni] = b2[e*DOUT + nb + ni*16 + l15];
  float gt[4][4];
  #pragma unroll
  for (int mi = 0; mi < 4; ++mi)
    #pragma unroll
    for (int r = 0; r < 4; ++r)
      gt[mi][r] = ew[(size_t)(M0 + mi*16 + g4*4 + r)*NE + e];
  #pragma unroll
  for (int mi = 0; mi < 4; ++mi)
    #pragma unroll
    for (int ni = 0; ni < 2; ++ni)
      #pragma unroll
      for (int r = 0; r < 4; ++r) {
        int tok = M0 + mi*16 + g4*4 + r;
        int o = nb + ni*16 + l15;
        out[(size_t)tok*(NE*DOUT) + e*DOUT + o] = (acc[mi][ni][r] + b2v[ni]) * gt[mi][r];
      }
}

// ---------------- expert counts + partial sums --------------------------------
__global__ void k_counts(const float* __restrict__ ew, float* __restrict__ counts,
                         float* __restrict__ partials) {
  __shared__ float sb[4];
  int g2 = blockIdx.x*256 + threadIdx.x;   // (t,e) flat, 0..8191
  float c = 0.f;
  #pragma unroll
  for (int b = 0; b < NB; ++b) c += ew[b*(NT*NE) + g2];
  counts[g2] = c;
  float tot = blk_sum(c, sb);
  if (threadIdx.x == 0) partials[blockIdx.x] = tot;
}

// ---------------- aux loss ----------------------------------------------------
__global__ void k_aux(const float* __restrict__ counts, const float* __restrict__ partials,
                      float* __restrict__ out) {
  __shared__ float sb[4];
  int tid = threadIdx.x;
  float pv = (tid < 32) ? partials[tid] : 0.f;
  float total = blk_sum(pv, sb);
  float invt = 1.0f / (total + FEPS);
  float sq = 0.f, ent = 0.f;
  for (int i2 = tid; i2 < NT*NE; i2 += 256) {
    float c = counts[i2];
    sq += c*c;
    float ld = c * invt;
    ent -= ld * logf(ld + FEPS);
  }
  sq = blk_sum(sq, sb);
  ent = blk_sum(ent, sb);
  if (tid == 0) {
    float var = (sq - total*total*(1.0f/(NT*NE))) * (1.0f/(NT*NE - 1));
    float stdv = sqrtf(fmaxf(var, 0.f));
    float ment = 0.f;
    #pragma unroll
    for (int e2 = 0; e2 < NE; ++e2) ment += out[ENT_OFF + e2];
    ment *= (1.0f/NE);
    out[AUX_OFF] = 0.5f*(stdv + ent) + 0.01f*ment;
  }
}

// ---------------- launch ------------------------------------------------------
extern "C" void kernel_launch(void* const* d_in, const int* in_sizes, int n_in,
                              void* d_out, int out_size, void* d_ws, size_t ws_size,
                              hipStream_t stream) {
  const float* h  = (const float*)d_in[0];
  const float* ce = (const float*)d_in[1];
  const float* gn = (const float*)d_in[2];
  const float* ca = (const float*)d_in[3];
  const float* fi = (const float*)d_in[4];
  const float* W1 = (const float*)d_in[5];
  const float* b1 = (const float*)d_in[6];
  const float* W2 = (const float*)d_in[7];
  const float* b2 = (const float*)d_in[8];
  float* out = (float*)d_out;
  char* ws = (char*)d_ws;
  // ws layout (bytes) — total 90,505,216 (Hbuf = [4][8192][1024] bf16 = 64MB)
  bf16*  w1t      = (bf16*)(ws);                 // [E][DH][DIN] bf16 (imp-folded): 10,485,760
  bf16*  w2t      = (bf16*)(ws + 10485760);      // [E][DOUT][DH] bf16: 2,097,152
  bf16*  xbuf     = (bf16*)(ws + 12582912);      // [8192][640] bf16: 10,485,760
  float* imp      = (float*)(ws + 23068672);     // [E][DIN]: 20,480
  float* anch     = (float*)(ws + 23089152);     // [E][CODE]: 8,192
  float* ew       = (float*)(ws + 23097344);     // [B][T][E]: 262,144
  float* counts   = (float*)(ws + 23359488);     // [T*E]: 32,768
  float* partials = (float*)(ws + 23392256);     // [32]: 128
  bf16*  Hbuf     = (bf16*)(ws + 23396352);      // [4][8192][1024] bf16: 67,108,864

  k_imp<<<dim3(8), dim3(256), 0, stream>>>(fi, imp, out);
  k_anchor_div<<<dim3(1), dim3(256), 0, stream>>>(ca, fi, anch, out);
  k_transpose<<<dim3(16, 10, 8), dim3(256), 0, stream>>>(W1, w1t, 640, 1024, imp);
  k_transpose<<<dim3(2, 16, 8), dim3(256), 0, stream>>>(W2, w2t, 1024, 128, nullptr);
  k_h2b<<<dim3(2560), dim3(256), 0, stream>>>(h, xbuf);
  k_router<<<dim3(2048), dim3(256), 0, stream>>>(ce, gn, anch, ew);
  k_g1<<<dim3(2048), dim3(256), 0, stream>>>(xbuf, w1t, b1, Hbuf, 0);
  k_g2<<<dim3(512), dim3(256), 0, stream>>>(Hbuf, w2t, b2, ew, out, 0);
  k_g1<<<dim3(2048), dim3(256), 0, stream>>>(xbuf, w1t, b1, Hbuf, 4);
  k_g2<<<dim3(512), dim3(256), 0, stream>>>(Hbuf, w2t, b2, ew, out, 4);
  k_counts<<<dim3(32), dim3(256), 0, stream>>>(ew, counts, partials);
  k_aux<<<dim3(1), dim3(256), 0, stream>>>(counts, partials, out);
}

// Round 12
// 202.227 us; speedup vs baseline: 3.1875x; 1.1586x over previous
//
#include <hip/hip_runtime.h>
#include <math.h>

#define DIN 640
#define DH 1024
#define DOUT 128
#define CODEDIM 256
#define NE 8
#define NB 8
#define NT 1024
#define NTOK 8192
#define TAU_INV 10.0f
#define FEPS 1e-8f

// out layout: full_output[8*1024*1024], aux[1], div[1], ent[8], mean[8], std[8]
#define AUX_OFF  8388608
#define DIV_OFF  8388609
#define ENT_OFF  8388610
#define MEAN_OFF 8388618
#define STD_OFF  8388626

typedef __bf16 bf16;
typedef bf16 bf16x8 __attribute__((ext_vector_type(8)));
typedef float f32x4 __attribute__((ext_vector_type(4)));

__device__ __forceinline__ float gelu(float x) {
  return 0.5f * x * (1.0f + erff(x * 0.70710678118654752f));
}

#define BAR() do { asm volatile("" ::: "memory"); __builtin_amdgcn_s_barrier(); asm volatile("" ::: "memory"); } while(0)
#define VMCNT6 asm volatile("s_waitcnt vmcnt(6)" ::: "memory")
#define VMCNT0 asm volatile("s_waitcnt vmcnt(0)" ::: "memory")

// async global->LDS, 16B/lane; LDS dest is wave-uniform base (HW adds lane*16);
// global source IS per-lane (pre-swizzled-global pattern, r5/r11-proven).
__device__ __forceinline__ void gload16(const void* g, void* l) {
  __builtin_amdgcn_global_load_lds(
      (const __attribute__((address_space(1))) unsigned int*)g,
      (__attribute__((address_space(3))) unsigned int*)l, 16, 0, 0);
}

// ---------------- block reduction helpers (blockDim multiple of 64) ----------
__device__ __forceinline__ float blk_sum(float v, float* sb) {
  #pragma unroll
  for (int o = 32; o > 0; o >>= 1) v += __shfl_down(v, o, 64);
  __syncthreads();
  if ((threadIdx.x & 63) == 0) sb[threadIdx.x >> 6] = v;
  __syncthreads();
  float tot = 0.f;
  int nw = blockDim.x >> 6;
  for (int i = 0; i < nw; ++i) tot += sb[i];
  return tot;
}

__device__ __forceinline__ float blk_max(float v, float* sb) {
  #pragma unroll
  for (int o = 32; o > 0; o >>= 1) v = fmaxf(v, __shfl_down(v, o, 64));
  __syncthreads();
  if ((threadIdx.x & 63) == 0) sb[threadIdx.x >> 6] = v;
  __syncthreads();
  float m = -3.0e38f;
  int nw = blockDim.x >> 6;
  for (int i = 0; i < nw; ++i) m = fmaxf(m, sb[i]);
  return m;
}

// ---------------- importance softmax + entropy/mean/std ---------------------
__global__ void k_imp(const float* __restrict__ fi, float* __restrict__ imp,
                      float* __restrict__ out) {
  __shared__ float sb[8];
  int e = blockIdx.x, tid = threadIdx.x;
  int d2v = tid + 512;
  float v0 = fi[e*DIN + tid] * 2.0f;          // /temp, temp = 0.5
  float v1 = fi[e*DIN + tid + 256] * 2.0f;
  float v2 = (d2v < DIN) ? fi[e*DIN + d2v] * 2.0f : -3.0e38f;
  float m = blk_max(fmaxf(v0, fmaxf(v1, v2)), sb);
  float e0 = expf(v0 - m), e1 = expf(v1 - m);
  float e2 = (d2v < DIN) ? expf(v2 - m) : 0.f;
  float s = blk_sum(e0 + e1 + e2, sb);
  float inv = 1.0f / s;
  float p0 = e0*inv, p1 = e1*inv, p2 = e2*inv;
  imp[e*DIN + tid] = p0;
  imp[e*DIN + tid + 256] = p1;
  if (d2v < DIN) imp[e*DIN + d2v] = p2;
  float ok2 = (d2v < DIN) ? 1.f : 0.f;
  float sp  = p0 + p1 + ok2*p2;
  float sp2 = p0*p0 + p1*p1 + ok2*p2*p2;
  float se  = p0*logf(p0 + FEPS) + p1*logf(p1 + FEPS) + ok2*p2*logf(p2 + FEPS);
  sp  = blk_sum(sp, sb);
  sp2 = blk_sum(sp2, sb);
  se  = blk_sum(se, sb);
  if (tid == 0) {
    out[ENT_OFF + e]  = -se;
    out[MEAN_OFF + e] = sp * (1.0f/DIN);
    float var = (sp2 - sp*sp*(1.0f/DIN)) * (1.0f/(DIN-1));
    out[STD_OFF + e]  = sqrtf(fmaxf(var, 0.f));
  }
}

// ---------------- anchor normalize + diversity loss --------------------------
__global__ void k_anchor_div(const float* __restrict__ ca, const float* __restrict__ fi,
                             float* __restrict__ anch, float* __restrict__ out) {
  __shared__ float sb[8];
  __shared__ float sd[256];
  int tid = threadIdx.x;
  for (int e = 0; e < NE; ++e) {
    float x = ca[e*CODEDIM + tid];
    float ss = blk_sum(x*x, sb);
    anch[e*CODEDIM + tid] = x / fmaxf(sqrtf(ss), 1e-12f);
  }
  // diversity: sim = fi @ fi^T, off-diag squared sum / 56
  int p = tid >> 2, q = tid & 3;     // pair p in 0..63, quarter q
  int i = p >> 3, j = p & 7;
  float dot = 0.f;
  for (int d = q*160; d < q*160 + 160; ++d) dot += fi[i*DIN + d] * fi[j*DIN + d];
  sd[tid] = dot;
  __syncthreads();
  if (tid < 64) {
    float s = sd[tid*4] + sd[tid*4+1] + sd[tid*4+2] + sd[tid*4+3];
    int ii = tid >> 3, jj = tid & 7;
    float val = (ii != jj) ? s*s : 0.f;
    #pragma unroll
    for (int o = 32; o > 0; o >>= 1) val += __shfl_down(val, o, 64);
    if (tid == 0) out[DIV_OFF] = val * (1.0f/56.0f);
  }
}

// -------- tiled transpose + f32->bf16 (+optional per-src-row scale) ----------
// src[e][R][C] -> dst[e][C][R]; dst[e][c][r] = src[e][r][c] * scale[e][r]
__global__ void k_transpose(const float* __restrict__ src, bf16* __restrict__ dst,
                            int R, int C, const float* __restrict__ scale) {
  __shared__ float tile[64][65];
  int c0 = blockIdx.x*64, r0 = blockIdx.y*64;
  int ee = blockIdx.z;
  const float* s = src + (size_t)ee*R*C;
  bf16* d = dst + (size_t)ee*C*R;
  int tx = threadIdx.x & 63, ty = threadIdx.x >> 6;
  #pragma unroll
  for (int p = 0; p < 16; ++p) {
    int r = p*4 + ty;
    tile[r][tx] = s[(size_t)(r0 + r)*C + c0 + tx];
  }
  __syncthreads();
  float sc = scale ? scale[(size_t)ee*R + r0 + tx] : 1.0f;
  #pragma unroll
  for (int p = 0; p < 16; ++p) {
    int cr = p*4 + ty;
    d[(size_t)(c0 + cr)*R + r0 + tx] = (bf16)(tile[tx][cr] * sc);
  }
}

// ---------------- h f32 -> bf16 (row-major, shared across experts) -----------
__global__ void k_h2b(const float* __restrict__ h, bf16* __restrict__ xb) {
  size_t i = (size_t)blockIdx.x*256 + threadIdx.x;   // 8 elements per thread
  const float4* p = (const float4*)(h + i*8);
  float4 v0 = p[0], v1 = p[1];
  bf16x8 o;
  o[0]=(bf16)v0.x; o[1]=(bf16)v0.y; o[2]=(bf16)v0.z; o[3]=(bf16)v0.w;
  o[4]=(bf16)v1.x; o[5]=(bf16)v1.y; o[6]=(bf16)v1.z; o[7]=(bf16)v1.w;
  *(bf16x8*)(xb + i*8) = o;
}

// ---------------- router: cosine logits + gumbel softmax ---------------------
__global__ void k_router(const float* __restrict__ ce, const float* __restrict__ gn,
                         const float* __restrict__ anch, float* __restrict__ ew) {
  __shared__ float anc[NE*CODEDIM];
  int tid = threadIdx.x;
  for (int i2 = tid; i2 < NE*CODEDIM; i2 += 256) anc[i2] = anch[i2];
  __syncthreads();
  int wv = tid >> 6, lane = tid & 63;
  int token = blockIdx.x*4 + wv;
  float4 x = *(const float4*)(ce + (size_t)token*CODEDIM + lane*4);
  float ss = x.x*x.x + x.y*x.y + x.z*x.z + x.w*x.w;
  #pragma unroll
  for (int o = 1; o < 64; o <<= 1) ss += __shfl_xor(ss, o, 64);
  float inv = 1.0f / fmaxf(sqrtf(ss), 1e-12f);
  const float* g = gn + (size_t)token*NE;
  float z[8];
  float m = -3.0e38f;
  #pragma unroll
  for (int e2 = 0; e2 < NE; ++e2) {
    const float* a = anc + e2*CODEDIM + lane*4;
    float d = x.x*a[0] + x.y*a[1] + x.z*a[2] + x.w*a[3];
    #pragma unroll
    for (int o = 1; o < 64; o <<= 1) d += __shfl_xor(d, o, 64);
    z[e2] = (d*inv + g[e2]) * TAU_INV;
    m = fmaxf(m, z[e2]);
  }
  float ssum = 0.f;
  float pz[8];
  #pragma unroll
  for (int e2 = 0; e2 < NE; ++e2) { pz[e2] = expf(z[e2] - m); ssum += pz[e2]; }
  float num = 0.f;
  #pragma unroll
  for (int e2 = 0; e2 < NE; ++e2) num = (lane == e2) ? pz[e2] : num;  // static idx
  if (lane < NE) ew[(size_t)token*NE + lane] = num / ssum;
}

// ================== GEMM1: H = gelu(X @ W1 + b1), bf16 out ===================
// m97-exact structure: 128(M)x128(N) tile, BK=64, SINGLE-buffered LDS 32KB
// (+272B-row epilogue overlay -> 34KB -> 4 blocks/CU), 10 K-steps, 2 barriers
// + vmcnt(0) drain per step; 32 MFMA per barrier-pair per wave (2x r11).
// Swizzle: slot ^= row&7 on 128B rows (r11-verified, conflicts 0.5M).
// Staged via inverse-swizzled per-lane GLOBAL source + linear LDS dest (T21).
// 32 consecutive bids share one A-panel (L2 reuse); bid&7 pins expert to XCDs.
#define G1_LDS 34816
__global__ __launch_bounds__(256, 3)
void k_g1(const bf16* __restrict__ xb, const bf16* __restrict__ w1t,
          const float* __restrict__ b1, bf16* __restrict__ Hb, int ebase) {
  __shared__ __align__(16) char L[G1_LDS];   // A [0,16K), B [16K,32K); overlay 128x272
  const int bid = blockIdx.x;
  const int el = bid & 3, e = ebase + el;
  const int nt = (bid >> 2) & 7, mt = bid >> 5;
  const int M0 = mt * 128, N0 = nt * 128;
  const int tid = threadIdx.x;
  const int lane = tid & 63, w = tid >> 6;
  const int l15 = lane & 15, g4 = lane >> 4;
  const int wr = w >> 1, wc = w & 1;           // 2x2 wave grid, each 64x64

  // per-lane inverse-swizzled global sources (involution on slot bits 4-6)
  const char* gAsrc[4];
  const char* gBsrc[4];
  #pragma unroll
  for (int j = 0; j < 4; ++j) {
    unsigned p = (unsigned)((w*4 + j)*1024 + lane*16);
    unsigned q = p ^ (((p >> 7) & 7u) << 4);
    gAsrc[j] = (const char*)xb + (size_t)(M0 + (int)(q >> 7))*(DIN*2) + (q & 127u);
    gBsrc[j] = (const char*)w1t + (size_t)(e*DH + N0 + (int)(q >> 7))*(DIN*2) + (q & 127u);
  }

  // swizzled fragment-read offsets (16-lane rows, slot^row&7 -> 2-way = free)
  unsigned afOff[4][2], bfOff[4][2];
  #pragma unroll
  for (int mi = 0; mi < 4; ++mi)
    #pragma unroll
    for (int kk = 0; kk < 2; ++kk) {
      int row = wr*64 + mi*16 + l15;
      int slot = kk*4 + g4;
      afOff[mi][kk] = (unsigned)(row*128 + ((slot ^ (row & 7)) << 4));
    }
  #pragma unroll
  for (int ni = 0; ni < 4; ++ni)
    #pragma unroll
    for (int kk = 0; kk < 2; ++kk) {
      int row = wc*64 + ni*16 + l15;
      int slot = kk*4 + g4;
      bfOff[ni][kk] = (unsigned)(16384 + row*128 + ((slot ^ (row & 7)) << 4));
    }

  f32x4 acc[4][4] = {};
  for (int t = 0; t < 10; ++t) {
    if (t) BAR();                    // all reads of tile t-1 done before restage
    size_t ko = (size_t)t * 128;     // 64 elems * 2B
    #pragma unroll
    for (int j = 0; j < 4; ++j) {
      gload16(gAsrc[j] + ko, L + (w*4 + j)*1024);
      gload16(gBsrc[j] + ko, L + 16384 + (w*4 + j)*1024);
    }
    VMCNT0;
    BAR();
    #pragma unroll
    for (int kk = 0; kk < 2; ++kk) {
      bf16x8 af[4], bfr[4];
      #pragma unroll
      for (int mi = 0; mi < 4; ++mi) af[mi] = *(const bf16x8*)(L + afOff[mi][kk]);
      #pragma unroll
      for (int ni = 0; ni < 4; ++ni) bfr[ni] = *(const bf16x8*)(L + bfOff[ni][kk]);
      #pragma unroll
      for (int mi = 0; mi < 4; ++mi)
        #pragma unroll
        for (int ni = 0; ni < 4; ++ni)
          acc[mi][ni] = __builtin_amdgcn_mfma_f32_16x16x32_bf16(
              af[mi], bfr[ni], acc[mi][ni], 0, 0, 0);
    }
  }
  BAR();                             // last reads done before epilogue overlay
  // epilogue: +b1, exact GELU -> LDS overlay (272B rows, 16-aligned,
  // conflict-free) -> coalesced bf16 stores (256B/row segments)
  float b1v[4];
  #pragma unroll
  for (int ni = 0; ni < 4; ++ni)
    b1v[ni] = b1[e*DH + N0 + wc*64 + ni*16 + l15];
  #pragma unroll
  for (int mi = 0; mi < 4; ++mi)
    #pragma unroll
    for (int ni = 0; ni < 4; ++ni)
      #pragma unroll
      for (int r = 0; r < 4; ++r) {
        float v = gelu(acc[mi][ni][r] + b1v[ni]);   // C/D: row=(l>>4)*4+r, col=l&15
        int row = wr*64 + mi*16 + g4*4 + r;
        int col = wc*64 + ni*16 + l15;
        *(bf16*)(L + row*272 + col*2) = (bf16)v;
      }
  __syncthreads();
  #pragma unroll
  for (int j = 0; j < 8; ++j) {
    int c = j*256 + tid;
    int row = c >> 4, slot = c & 15;     // 128 rows x 16 slots of 16B
    bf16x8 v = *(const bf16x8*)(L + row*272 + slot*16);
    *(bf16x8*)((char*)Hb + (size_t)(el*NTOK + M0 + row)*(DH*2) + (size_t)N0*2 + slot*16) = v;
  }
}

// ================== GEMM2: out = (H @ W2 + b2) * gate, f32 ===================
// r11-proven (keep): tile 64(M)x128(N=DOUT), BK=64, 16 steps, dbuf, counted
// vmcnt(6); 4 waves each 64x32 (acc 4x2). Swizzle slot^row&7 on 128B rows.
__global__ __launch_bounds__(256, 3)
void k_g2(const bf16* __restrict__ Hb, const bf16* __restrict__ w2t,
          const float* __restrict__ b2, const float* __restrict__ ew,
          float* __restrict__ out, int ebase) {
  __shared__ __align__(16) char L[49152];
  const int bid = blockIdx.x;
  const int el = bid & 3, e = ebase + el;
  const int mt = bid >> 2;
  const int M0 = mt * 64;
  const int tid = threadIdx.x;
  const int lane = tid & 63, w = tid >> 6;
  const int l15 = lane & 15, g4 = lane >> 4;
  const int nb = w * 32;

  const char* gAsrc[2];
  #pragma unroll
  for (int j = 0; j < 2; ++j) {
    unsigned p = (unsigned)((w*2 + j)*1024 + lane*16);
    unsigned q = p ^ (((p >> 7) & 7u) << 4);
    gAsrc[j] = (const char*)Hb + (size_t)(el*NTOK + M0 + (int)(q >> 7))*(DH*2) + (q & 127u);
  }
  const char* gBsrc[4];
  #pragma unroll
  for (int j = 0; j < 4; ++j) {
    unsigned p = (unsigned)((w*4 + j)*1024 + lane*16);
    unsigned q = p ^ (((p >> 7) & 7u) << 4);
    gBsrc[j] = (const char*)w2t + (size_t)(e*DOUT + (int)(q >> 7))*(DH*2) + (q & 127u);
  }
  auto STAGE = [&](int buf, int t) {
    size_t ko = (size_t)t * 128;
    #pragma unroll
    for (int j = 0; j < 2; ++j)
      gload16(gAsrc[j] + ko, L + buf*8192 + (w*2 + j)*1024);
    #pragma unroll
    for (int j = 0; j < 4; ++j)
      gload16(gBsrc[j] + ko, L + 16384 + buf*16384 + (w*4 + j)*1024);
  };

  unsigned afOff[4][2], bfOff[2][2];
  #pragma unroll
  for (int mi = 0; mi < 4; ++mi)
    #pragma unroll
    for (int kk = 0; kk < 2; ++kk) {
      int row = mi*16 + l15;
      int slot = kk*4 + g4;
      afOff[mi][kk] = (unsigned)(row*128 + ((slot ^ (row & 7)) << 4));
    }
  #pragma unroll
  for (int ni = 0; ni < 2; ++ni)
    #pragma unroll
    for (int kk = 0; kk < 2; ++kk) {
      int row = nb + ni*16 + l15;
      int slot = kk*4 + g4;
      bfOff[ni][kk] = (unsigned)(row*128 + ((slot ^ (row & 7)) << 4));
    }

  f32x4 acc[4][2] = {};
  STAGE(0, 0);
  for (int t = 0; t < 16; ++t) {
    int buf = t & 1;
    if (t < 15) { STAGE(buf ^ 1, t + 1); VMCNT6; } else { VMCNT0; }
    BAR();
    const char* Ab = L + buf*8192;
    const char* Bb = L + 16384 + buf*16384;
    #pragma unroll
    for (int kk = 0; kk < 2; ++kk) {
      bf16x8 af[4], bfr[2];
      #pragma unroll
      for (int mi = 0; mi < 4; ++mi) af[mi] = *(const bf16x8*)(Ab + afOff[mi][kk]);
      #pragma unroll
      for (int ni = 0; ni < 2; ++ni) bfr[ni] = *(const bf16x8*)(Bb + bfOff[ni][kk]);
      #pragma unroll
      for (int mi = 0; mi < 4; ++mi)
        #pragma unroll
        for (int ni = 0; ni < 2; ++ni)
          acc[mi][ni] = __builtin_amdgcn_mfma_f32_16x16x32_bf16(
              af[mi], bfr[ni], acc[mi][ni], 0, 0, 0);
    }
    BAR();
  }
  // epilogue: +b2, *gate, direct f32 stores (16-lane groups -> 64B segments)
  float b2v[2];
  #pragma unroll
  for (int ni = 0; ni < 2; ++ni)
    b2v[ni] = b2[e*DOUT + nb + ni*16 + l15];
  float gt[4][4];
  #pragma unroll
  for (int mi = 0; mi < 4; ++mi)
    #pragma unroll
    for (int r = 0; r < 4; ++r)
      gt[mi][r] = ew[(size_t)(M0 + mi*16 + g4*4 + r)*NE + e];
  #pragma unroll
  for (int mi = 0; mi < 4; ++mi)
    #pragma unroll
    for (int ni = 0; ni < 2; ++ni)
      #pragma unroll
      for (int r = 0; r < 4; ++r) {
        int tok = M0 + mi*16 + g4*4 + r;
        int o = nb + ni*16 + l15;
        out[(size_t)tok*(NE*DOUT) + e*DOUT + o] = (acc[mi][ni][r] + b2v[ni]) * gt[mi][r];
      }
}

// ---------------- expert counts + partial sums --------------------------------
__global__ void k_counts(const float* __restrict__ ew, float* __restrict__ counts,
                         float* __restrict__ partials) {
  __shared__ float sb[4];
  int g2 = blockIdx.x*256 + threadIdx.x;   // (t,e) flat, 0..8191
  float c = 0.f;
  #pragma unroll
  for (int b = 0; b < NB; ++b) c += ew[b*(NT*NE) + g2];
  counts[g2] = c;
  float tot = blk_sum(c, sb);
  if (threadIdx.x == 0) partials[blockIdx.x] = tot;
}

// ---------------- aux loss ----------------------------------------------------
__global__ void k_aux(const float* __restrict__ counts, const float* __restrict__ partials,
                      float* __restrict__ out) {
  __shared__ float sb[4];
  int tid = threadIdx.x;
  float pv = (tid < 32) ? partials[tid] : 0.f;
  float total = blk_sum(pv, sb);
  float invt = 1.0f / (total + FEPS);
  float sq = 0.f, ent = 0.f;
  for (int i2 = tid; i2 < NT*NE; i2 += 256) {
    float c = counts[i2];
    sq += c*c;
    float ld = c * invt;
    ent -= ld * logf(ld + FEPS);
  }
  sq = blk_sum(sq, sb);
  ent = blk_sum(ent, sb);
  if (tid == 0) {
    float var = (sq - total*total*(1.0f/(NT*NE))) * (1.0f/(NT*NE - 1));
    float stdv = sqrtf(fmaxf(var, 0.f));
    float ment = 0.f;
    #pragma unroll
    for (int e2 = 0; e2 < NE; ++e2) ment += out[ENT_OFF + e2];
    ment *= (1.0f/NE);
    out[AUX_OFF] = 0.5f*(stdv + ent) + 0.01f*ment;
  }
}

// ---------------- launch ------------------------------------------------------
extern "C" void kernel_launch(void* const* d_in, const int* in_sizes, int n_in,
                              void* d_out, int out_size, void* d_ws, size_t ws_size,
                              hipStream_t stream) {
  const float* h  = (const float*)d_in[0];
  const float* ce = (const float*)d_in[1];
  const float* gn = (const float*)d_in[2];
  const float* ca = (const float*)d_in[3];
  const float* fi = (const float*)d_in[4];
  const float* W1 = (const float*)d_in[5];
  const float* b1 = (const float*)d_in[6];
  const float* W2 = (const float*)d_in[7];
  const float* b2 = (const float*)d_in[8];
  float* out = (float*)d_out;
  char* ws = (char*)d_ws;
  // ws layout (bytes) — total 90,505,216 (Hbuf = [4][8192][1024] bf16 = 64MB)
  bf16*  w1t      = (bf16*)(ws);                 // [E][DH][DIN] bf16 (imp-folded): 10,485,760
  bf16*  w2t      = (bf16*)(ws + 10485760);      // [E][DOUT][DH] bf16: 2,097,152
  bf16*  xbuf     = (bf16*)(ws + 12582912);      // [8192][640] bf16: 10,485,760
  float* imp      = (float*)(ws + 23068672);     // [E][DIN]: 20,480
  float* anch     = (float*)(ws + 23089152);     // [E][CODE]: 8,192
  float* ew       = (float*)(ws + 23097344);     // [B][T][E]: 262,144
  float* counts   = (float*)(ws + 23359488);     // [T*E]: 32,768
  float* partials = (float*)(ws + 23392256);     // [32]: 128
  bf16*  Hbuf     = (bf16*)(ws + 23396352);      // [4][8192][1024] bf16: 67,108,864

  k_imp<<<dim3(8), dim3(256), 0, stream>>>(fi, imp, out);
  k_anchor_div<<<dim3(1), dim3(256), 0, stream>>>(ca, fi, anch, out);
  k_transpose<<<dim3(16, 10, 8), dim3(256), 0, stream>>>(W1, w1t, 640, 1024, imp);
  k_transpose<<<dim3(2, 16, 8), dim3(256), 0, stream>>>(W2, w2t, 1024, 128, nullptr);
  k_h2b<<<dim3(2560), dim3(256), 0, stream>>>(h, xbuf);
  k_router<<<dim3(2048), dim3(256), 0, stream>>>(ce, gn, anch, ew);
  k_g1<<<dim3(2048), dim3(256), 0, stream>>>(xbuf, w1t, b1, Hbuf, 0);
  k_g2<<<dim3(512), dim3(256), 0, stream>>>(Hbuf, w2t, b2, ew, out, 0);
  k_g1<<<dim3(2048), dim3(256), 0, stream>>>(xbuf, w1t, b1, Hbuf, 4);
  k_g2<<<dim3(512), dim3(256), 0, stream>>>(Hbuf, w2t, b2, ew, out, 4);
  k_counts<<<dim3(32), dim3(256), 0, stream>>>(ew, counts, partials);
  k_aux<<<dim3(1), dim3(256), 0, stream>>>(counts, partials, out);
}

// Round 13
// 187.779 us; speedup vs baseline: 3.4327x; 1.0769x over previous
//
#include <hip/hip_runtime.h>
#include <math.h>

#define DIN 640
#define DH 1024
#define DOUT 128
#define CODEDIM 256
#define NE 8
#define NB 8
#define NT 1024
#define NTOK 8192
#define TAU_INV 10.0f
#define FEPS 1e-8f

// out layout: full_output[8*1024*1024], aux[1], div[1], ent[8], mean[8], std[8]
#define AUX_OFF  8388608
#define DIV_OFF  8388609
#define ENT_OFF  8388610
#define MEAN_OFF 8388618
#define STD_OFF  8388626

typedef __bf16 bf16;
typedef bf16 bf16x8 __attribute__((ext_vector_type(8)));
typedef float f32x4 __attribute__((ext_vector_type(4)));

__device__ __forceinline__ float gelu(float x) {
  return 0.5f * x * (1.0f + erff(x * 0.70710678118654752f));
}

#define BAR() do { asm volatile("" ::: "memory"); __builtin_amdgcn_s_barrier(); asm volatile("" ::: "memory"); } while(0)
#define VMCNT6 asm volatile("s_waitcnt vmcnt(6)" ::: "memory")
#define VMCNT0 asm volatile("s_waitcnt vmcnt(0)" ::: "memory")

// async global->LDS, 16B/lane; LDS dest is wave-uniform base (HW adds lane*16);
// global source IS per-lane (pre-swizzled-global pattern, r5/r11-proven).
__device__ __forceinline__ void gload16(const void* g, void* l) {
  __builtin_amdgcn_global_load_lds(
      (const __attribute__((address_space(1))) unsigned int*)g,
      (__attribute__((address_space(3))) unsigned int*)l, 16, 0, 0);
}

// ---------------- block reduction helpers (blockDim multiple of 64) ----------
__device__ __forceinline__ float blk_sum(float v, float* sb) {
  #pragma unroll
  for (int o = 32; o > 0; o >>= 1) v += __shfl_down(v, o, 64);
  __syncthreads();
  if ((threadIdx.x & 63) == 0) sb[threadIdx.x >> 6] = v;
  __syncthreads();
  float tot = 0.f;
  int nw = blockDim.x >> 6;
  for (int i = 0; i < nw; ++i) tot += sb[i];
  return tot;
}

__device__ __forceinline__ float blk_max(float v, float* sb) {
  #pragma unroll
  for (int o = 32; o > 0; o >>= 1) v = fmaxf(v, __shfl_down(v, o, 64));
  __syncthreads();
  if ((threadIdx.x & 63) == 0) sb[threadIdx.x >> 6] = v;
  __syncthreads();
  float m = -3.0e38f;
  int nw = blockDim.x >> 6;
  for (int i = 0; i < nw; ++i) m = fmaxf(m, sb[i]);
  return m;
}

// ================== fused prep: 6 roles in one launch =========================
// [0,1280)    role A: W1 transpose + inline importance scale -> w1t
// [1280,1536) role B: W2 transpose -> w2t
// [1536,4096) role C: h f32 -> bf16 (xbuf)
// [4096,6144) role D: router (inline anchor norms) -> ew
// [6144,6152) role E: importance stats -> out[ENT/MEAN/STD]
// [6152]      role F: diversity loss -> out[DIV]
// Roles are independent (no cross-block deps: A computes softmax inline,
// D normalizes anchors inline) so one launch is race-free.
__global__ __launch_bounds__(256)
void k_prep(const float* __restrict__ h, const float* __restrict__ ce,
            const float* __restrict__ gn, const float* __restrict__ ca,
            const float* __restrict__ fi, const float* __restrict__ W1,
            const float* __restrict__ W2,
            bf16* __restrict__ w1t, bf16* __restrict__ w2t,
            bf16* __restrict__ xb, float* __restrict__ ew,
            float* __restrict__ out) {
  const int bid = blockIdx.x;
  const int tid = threadIdx.x;
  if (bid < 1280) {
    // ---- role A: W1[e][640][1024] -> w1t[e][1024][640]*imp, imp inline ----
    __shared__ float tile[64][65];
    __shared__ float sb[8];
    __shared__ float red[2];
    int c0 = (bid & 15) * 64;
    int r0 = ((bid >> 4) % 10) * 64;
    int ee = bid / 160;
    const float* s = W1 + (size_t)ee*DIN*DH;
    bf16* d = w1t + (size_t)ee*DH*DIN;
    int i2v = tid + 512;
    float v0 = fi[ee*DIN + tid] * 2.0f;
    float v1 = fi[ee*DIN + tid + 256] * 2.0f;
    float v2 = (i2v < DIN) ? fi[ee*DIN + i2v] * 2.0f : -3.0e38f;
    float m = blk_max(fmaxf(v0, fmaxf(v1, v2)), sb);
    float se = expf(v0 - m) + expf(v1 - m) + ((i2v < DIN) ? expf(v2 - m) : 0.f);
    float ssum = blk_sum(se, sb);
    if (tid == 0) { red[0] = m; red[1] = 1.0f / ssum; }
    int tx = tid & 63, ty = tid >> 6;
    #pragma unroll
    for (int p = 0; p < 16; ++p) {
      int r = p*4 + ty;
      tile[r][tx] = s[(size_t)(r0 + r)*DH + c0 + tx];
    }
    __syncthreads();
    float sc = expf(fi[ee*DIN + r0 + tx]*2.0f - red[0]) * red[1];
    #pragma unroll
    for (int p = 0; p < 16; ++p) {
      int cr = p*4 + ty;
      d[(size_t)(c0 + cr)*DIN + r0 + tx] = (bf16)(tile[tx][cr] * sc);
    }
  } else if (bid < 1536) {
    // ---- role B: W2[e][1024][128] -> w2t[e][128][1024] ----
    __shared__ float tile[64][65];
    int c = bid - 1280;
    int c0 = (c & 1) * 64;
    int r0 = ((c >> 1) & 15) * 64;
    int ee = c >> 5;
    const float* s = W2 + (size_t)ee*DH*DOUT;
    bf16* d = w2t + (size_t)ee*DOUT*DH;
    int tx = tid & 63, ty = tid >> 6;
    #pragma unroll
    for (int p = 0; p < 16; ++p) {
      int r = p*4 + ty;
      tile[r][tx] = s[(size_t)(r0 + r)*DOUT + c0 + tx];
    }
    __syncthreads();
    #pragma unroll
    for (int p = 0; p < 16; ++p) {
      int cr = p*4 + ty;
      d[(size_t)(c0 + cr)*DH + r0 + tx] = (bf16)tile[tx][cr];
    }
  } else if (bid < 4096) {
    // ---- role C: h f32 -> bf16 ----
    size_t i = (size_t)(bid - 1536)*256 + tid;
    const float4* p = (const float4*)(h + i*8);
    float4 u0 = p[0], u1 = p[1];
    bf16x8 o;
    o[0]=(bf16)u0.x; o[1]=(bf16)u0.y; o[2]=(bf16)u0.z; o[3]=(bf16)u0.w;
    o[4]=(bf16)u1.x; o[5]=(bf16)u1.y; o[6]=(bf16)u1.z; o[7]=(bf16)u1.w;
    *(bf16x8*)(xb + i*8) = o;
  } else if (bid < 6144) {
    // ---- role D: router, anchors normalized inline ----
    __shared__ float anc[NE*CODEDIM];
    __shared__ float sd[256];
    __shared__ float invn[8];
    int c = bid - 4096;
    for (int i = tid; i < NE*CODEDIM; i += 256) anc[i] = ca[i];
    __syncthreads();
    {
      int e8 = tid >> 5, base = e8*CODEDIM + (tid & 31)*8;
      float ps = 0.f;
      #pragma unroll
      for (int j = 0; j < 8; ++j) { float v = anc[base + j]; ps += v*v; }
      sd[tid] = ps;
    }
    __syncthreads();
    if (tid < 8) {
      float s2 = 0.f;
      for (int j = 0; j < 32; ++j) s2 += sd[tid*32 + j];
      invn[tid] = 1.0f / fmaxf(sqrtf(s2), 1e-12f);
    }
    __syncthreads();
    int wv = tid >> 6, lane = tid & 63;
    int token = c*4 + wv;
    float4 x = *(const float4*)(ce + (size_t)token*CODEDIM + lane*4);
    float ss = x.x*x.x + x.y*x.y + x.z*x.z + x.w*x.w;
    #pragma unroll
    for (int o = 1; o < 64; o <<= 1) ss += __shfl_xor(ss, o, 64);
    float invx = 1.0f / fmaxf(sqrtf(ss), 1e-12f);
    const float* g = gn + (size_t)token*NE;
    float z[8];
    float m = -3.0e38f;
    #pragma unroll
    for (int e2 = 0; e2 < NE; ++e2) {
      const float* a = anc + e2*CODEDIM + lane*4;
      float d = x.x*a[0] + x.y*a[1] + x.z*a[2] + x.w*a[3];
      #pragma unroll
      for (int o = 1; o < 64; o <<= 1) d += __shfl_xor(d, o, 64);
      z[e2] = (d * invx * invn[e2] + g[e2]) * TAU_INV;
      m = fmaxf(m, z[e2]);
    }
    float ssum = 0.f;
    float pz[8];
    #pragma unroll
    for (int e2 = 0; e2 < NE; ++e2) { pz[e2] = expf(z[e2] - m); ssum += pz[e2]; }
    float num = 0.f;
    #pragma unroll
    for (int e2 = 0; e2 < NE; ++e2) num = (lane == e2) ? pz[e2] : num;
    if (lane < NE) ew[(size_t)token*NE + lane] = num / ssum;
  } else if (bid < 6152) {
    // ---- role E: importance stats (ENT/MEAN/STD) ----
    __shared__ float sb[8];
    int e = bid - 6144;
    int d2v = tid + 512;
    float v0 = fi[e*DIN + tid] * 2.0f;
    float v1 = fi[e*DIN + tid + 256] * 2.0f;
    float v2 = (d2v < DIN) ? fi[e*DIN + d2v] * 2.0f : -3.0e38f;
    float m = blk_max(fmaxf(v0, fmaxf(v1, v2)), sb);
    float e0 = expf(v0 - m), e1 = expf(v1 - m);
    float e2 = (d2v < DIN) ? expf(v2 - m) : 0.f;
    float s = blk_sum(e0 + e1 + e2, sb);
    float inv = 1.0f / s;
    float p0 = e0*inv, p1 = e1*inv, p2 = e2*inv;
    float ok2 = (d2v < DIN) ? 1.f : 0.f;
    float sp  = p0 + p1 + ok2*p2;
    float sp2 = p0*p0 + p1*p1 + ok2*p2*p2;
    float sent = p0*logf(p0 + FEPS) + p1*logf(p1 + FEPS) + ok2*p2*logf(p2 + FEPS);
    sp   = blk_sum(sp, sb);
    sp2  = blk_sum(sp2, sb);
    sent = blk_sum(sent, sb);
    if (tid == 0) {
      out[ENT_OFF + e]  = -sent;
      out[MEAN_OFF + e] = sp * (1.0f/DIN);
      float var = (sp2 - sp*sp*(1.0f/DIN)) * (1.0f/(DIN-1));
      out[STD_OFF + e]  = sqrtf(fmaxf(var, 0.f));
    }
  } else {
    // ---- role F: diversity loss ----
    __shared__ float sd[256];
    int p = tid >> 2, q = tid & 3;
    int i = p >> 3, j = p & 7;
    float dot = 0.f;
    for (int d = q*160; d < q*160 + 160; ++d) dot += fi[i*DIN + d] * fi[j*DIN + d];
    sd[tid] = dot;
    __syncthreads();
    if (tid < 64) {
      float s = sd[tid*4] + sd[tid*4+1] + sd[tid*4+2] + sd[tid*4+3];
      int ii = tid >> 3, jj = tid & 7;
      float val = (ii != jj) ? s*s : 0.f;
      #pragma unroll
      for (int o = 32; o > 0; o >>= 1) val += __shfl_down(val, o, 64);
      if (tid == 0) out[DIV_OFF] = val * (1.0f/56.0f);
    }
  }
}

// ================== GEMM1: H = gelu(X @ W1 + b1), bf16 out ===================
// r12-proven (FROZEN): m97 structure, 128x128 tile, BK=64, single-buffered,
// swizzle slot^row&7, inverse-swizzled global sources, 3 blocks/CU.
#define G1_LDS 34816
__global__ __launch_bounds__(256, 3)
void k_g1(const bf16* __restrict__ xb, const bf16* __restrict__ w1t,
          const float* __restrict__ b1, bf16* __restrict__ Hb, int ebase) {
  __shared__ __align__(16) char L[G1_LDS];
  const int bid = blockIdx.x;
  const int el = bid & 3, e = ebase + el;
  const int nt = (bid >> 2) & 7, mt = bid >> 5;
  const int M0 = mt * 128, N0 = nt * 128;
  const int tid = threadIdx.x;
  const int lane = tid & 63, w = tid >> 6;
  const int l15 = lane & 15, g4 = lane >> 4;
  const int wr = w >> 1, wc = w & 1;

  const char* gAsrc[4];
  const char* gBsrc[4];
  #pragma unroll
  for (int j = 0; j < 4; ++j) {
    unsigned p = (unsigned)((w*4 + j)*1024 + lane*16);
    unsigned q = p ^ (((p >> 7) & 7u) << 4);
    gAsrc[j] = (const char*)xb + (size_t)(M0 + (int)(q >> 7))*(DIN*2) + (q & 127u);
    gBsrc[j] = (const char*)w1t + (size_t)(e*DH + N0 + (int)(q >> 7))*(DIN*2) + (q & 127u);
  }

  unsigned afOff[4][2], bfOff[4][2];
  #pragma unroll
  for (int mi = 0; mi < 4; ++mi)
    #pragma unroll
    for (int kk = 0; kk < 2; ++kk) {
      int row = wr*64 + mi*16 + l15;
      int slot = kk*4 + g4;
      afOff[mi][kk] = (unsigned)(row*128 + ((slot ^ (row & 7)) << 4));
    }
  #pragma unroll
  for (int ni = 0; ni < 4; ++ni)
    #pragma unroll
    for (int kk = 0; kk < 2; ++kk) {
      int row = wc*64 + ni*16 + l15;
      int slot = kk*4 + g4;
      bfOff[ni][kk] = (unsigned)(16384 + row*128 + ((slot ^ (row & 7)) << 4));
    }

  f32x4 acc[4][4] = {};
  for (int t = 0; t < 10; ++t) {
    if (t) BAR();
    size_t ko = (size_t)t * 128;
    #pragma unroll
    for (int j = 0; j < 4; ++j) {
      gload16(gAsrc[j] + ko, L + (w*4 + j)*1024);
      gload16(gBsrc[j] + ko, L + 16384 + (w*4 + j)*1024);
    }
    VMCNT0;
    BAR();
    #pragma unroll
    for (int kk = 0; kk < 2; ++kk) {
      bf16x8 af[4], bfr[4];
      #pragma unroll
      for (int mi = 0; mi < 4; ++mi) af[mi] = *(const bf16x8*)(L + afOff[mi][kk]);
      #pragma unroll
      for (int ni = 0; ni < 4; ++ni) bfr[ni] = *(const bf16x8*)(L + bfOff[ni][kk]);
      #pragma unroll
      for (int mi = 0; mi < 4; ++mi)
        #pragma unroll
        for (int ni = 0; ni < 4; ++ni)
          acc[mi][ni] = __builtin_amdgcn_mfma_f32_16x16x32_bf16(
              af[mi], bfr[ni], acc[mi][ni], 0, 0, 0);
    }
  }
  BAR();
  float b1v[4];
  #pragma unroll
  for (int ni = 0; ni < 4; ++ni)
    b1v[ni] = b1[e*DH + N0 + wc*64 + ni*16 + l15];
  #pragma unroll
  for (int mi = 0; mi < 4; ++mi)
    #pragma unroll
    for (int ni = 0; ni < 4; ++ni)
      #pragma unroll
      for (int r = 0; r < 4; ++r) {
        float v = gelu(acc[mi][ni][r] + b1v[ni]);
        int row = wr*64 + mi*16 + g4*4 + r;
        int col = wc*64 + ni*16 + l15;
        *(bf16*)(L + row*272 + col*2) = (bf16)v;
      }
  __syncthreads();
  #pragma unroll
  for (int j = 0; j < 8; ++j) {
    int c = j*256 + tid;
    int row = c >> 4, slot = c & 15;
    bf16x8 v = *(const bf16x8*)(L + row*272 + slot*16);
    *(bf16x8*)((char*)Hb + (size_t)(el*NTOK + M0 + row)*(DH*2) + (size_t)N0*2 + slot*16) = v;
  }
}

// ================== GEMM2: out = (H @ W2 + b2) * gate, f32 ===================
// r11-proven (FROZEN): 64x128 tile, BK=64, dbuf, counted vmcnt(6).
__global__ __launch_bounds__(256, 3)
void k_g2(const bf16* __restrict__ Hb, const bf16* __restrict__ w2t,
          const float* __restrict__ b2, const float* __restrict__ ew,
          float* __restrict__ out, int ebase) {
  __shared__ __align__(16) char L[49152];
  const int bid = blockIdx.x;
  const int el = bid & 3, e = ebase + el;
  const int mt = bid >> 2;
  const int M0 = mt * 64;
  const int tid = threadIdx.x;
  const int lane = tid & 63, w = tid >> 6;
  const int l15 = lane & 15, g4 = lane >> 4;
  const int nb = w * 32;

  const char* gAsrc[2];
  #pragma unroll
  for (int j = 0; j < 2; ++j) {
    unsigned p = (unsigned)((w*2 + j)*1024 + lane*16);
    unsigned q = p ^ (((p >> 7) & 7u) << 4);
    gAsrc[j] = (const char*)Hb + (size_t)(el*NTOK + M0 + (int)(q >> 7))*(DH*2) + (q & 127u);
  }
  const char* gBsrc[4];
  #pragma unroll
  for (int j = 0; j < 4; ++j) {
    unsigned p = (unsigned)((w*4 + j)*1024 + lane*16);
    unsigned q = p ^ (((p >> 7) & 7u) << 4);
    gBsrc[j] = (const char*)w2t + (size_t)(e*DOUT + (int)(q >> 7))*(DH*2) + (q & 127u);
  }
  auto STAGE = [&](int buf, int t) {
    size_t ko = (size_t)t * 128;
    #pragma unroll
    for (int j = 0; j < 2; ++j)
      gload16(gAsrc[j] + ko, L + buf*8192 + (w*2 + j)*1024);
    #pragma unroll
    for (int j = 0; j < 4; ++j)
      gload16(gBsrc[j] + ko, L + 16384 + buf*16384 + (w*4 + j)*1024);
  };

  unsigned afOff[4][2], bfOff[2][2];
  #pragma unroll
  for (int mi = 0; mi < 4; ++mi)
    #pragma unroll
    for (int kk = 0; kk < 2; ++kk) {
      int row = mi*16 + l15;
      int slot = kk*4 + g4;
      afOff[mi][kk] = (unsigned)(row*128 + ((slot ^ (row & 7)) << 4));
    }
  #pragma unroll
  for (int ni = 0; ni < 2; ++ni)
    #pragma unroll
    for (int kk = 0; kk < 2; ++kk) {
      int row = nb + ni*16 + l15;
      int slot = kk*4 + g4;
      bfOff[ni][kk] = (unsigned)(row*128 + ((slot ^ (row & 7)) << 4));
    }

  f32x4 acc[4][2] = {};
  STAGE(0, 0);
  for (int t = 0; t < 16; ++t) {
    int buf = t & 1;
    if (t < 15) { STAGE(buf ^ 1, t + 1); VMCNT6; } else { VMCNT0; }
    BAR();
    const char* Ab = L + buf*8192;
    const char* Bb = L + 16384 + buf*16384;
    #pragma unroll
    for (int kk = 0; kk < 2; ++kk) {
      bf16x8 af[4], bfr[2];
      #pragma unroll
      for (int mi = 0; mi < 4; ++mi) af[mi] = *(const bf16x8*)(Ab + afOff[mi][kk]);
      #pragma unroll
      for (int ni = 0; ni < 2; ++ni) bfr[ni] = *(const bf16x8*)(Bb + bfOff[ni][kk]);
      #pragma unroll
      for (int mi = 0; mi < 4; ++mi)
        #pragma unroll
        for (int ni = 0; ni < 2; ++ni)
          acc[mi][ni] = __builtin_amdgcn_mfma_f32_16x16x32_bf16(
              af[mi], bfr[ni], acc[mi][ni], 0, 0, 0);
    }
    BAR();
  }
  float b2v[2];
  #pragma unroll
  for (int ni = 0; ni < 2; ++ni)
    b2v[ni] = b2[e*DOUT + nb + ni*16 + l15];
  float gt[4][4];
  #pragma unroll
  for (int mi = 0; mi < 4; ++mi)
    #pragma unroll
    for (int r = 0; r < 4; ++r)
      gt[mi][r] = ew[(size_t)(M0 + mi*16 + g4*4 + r)*NE + e];
  #pragma unroll
  for (int mi = 0; mi < 4; ++mi)
    #pragma unroll
    for (int ni = 0; ni < 2; ++ni)
      #pragma unroll
      for (int r = 0; r < 4; ++r) {
        int tok = M0 + mi*16 + g4*4 + r;
        int o = nb + ni*16 + l15;
        out[(size_t)tok*(NE*DOUT) + e*DOUT + o] = (acc[mi][ni][r] + b2v[ni]) * gt[mi][r];
      }
}

// ---------------- expert counts + partial sums --------------------------------
__global__ void k_counts(const float* __restrict__ ew, float* __restrict__ counts,
                         float* __restrict__ partials) {
  __shared__ float sb[4];
  int g2 = blockIdx.x*256 + threadIdx.x;
  float c = 0.f;
  #pragma unroll
  for (int b = 0; b < NB; ++b) c += ew[b*(NT*NE) + g2];
  counts[g2] = c;
  float tot = blk_sum(c, sb);
  if (threadIdx.x == 0) partials[blockIdx.x] = tot;
}

// ---------------- aux loss ----------------------------------------------------
__global__ void k_aux(const float* __restrict__ counts, const float* __restrict__ partials,
                      float* __restrict__ out) {
  __shared__ float sb[4];
  int tid = threadIdx.x;
  float pv = (tid < 32) ? partials[tid] : 0.f;
  float total = blk_sum(pv, sb);
  float invt = 1.0f / (total + FEPS);
  float sq = 0.f, ent = 0.f;
  for (int i2 = tid; i2 < NT*NE; i2 += 256) {
    float c = counts[i2];
    sq += c*c;
    float ld = c * invt;
    ent -= ld * logf(ld + FEPS);
  }
  sq = blk_sum(sq, sb);
  ent = blk_sum(ent, sb);
  if (tid == 0) {
    float var = (sq - total*total*(1.0f/(NT*NE))) * (1.0f/(NT*NE - 1));
    float stdv = sqrtf(fmaxf(var, 0.f));
    float ment = 0.f;
    #pragma unroll
    for (int e2 = 0; e2 < NE; ++e2) ment += out[ENT_OFF + e2];
    ment *= (1.0f/NE);
    out[AUX_OFF] = 0.5f*(stdv + ent) + 0.01f*ment;
  }
}

// ---------------- launch ------------------------------------------------------
extern "C" void kernel_launch(void* const* d_in, const int* in_sizes, int n_in,
                              void* d_out, int out_size, void* d_ws, size_t ws_size,
                              hipStream_t stream) {
  const float* h  = (const float*)d_in[0];
  const float* ce = (const float*)d_in[1];
  const float* gn = (const float*)d_in[2];
  const float* ca = (const float*)d_in[3];
  const float* fi = (const float*)d_in[4];
  const float* W1 = (const float*)d_in[5];
  const float* b1 = (const float*)d_in[6];
  const float* W2 = (const float*)d_in[7];
  const float* b2 = (const float*)d_in[8];
  float* out = (float*)d_out;
  char* ws = (char*)d_ws;
  // ws layout (bytes) — total 90,505,216 (Hbuf = [4][8192][1024] bf16 = 64MB)
  bf16*  w1t      = (bf16*)(ws);                 // [E][DH][DIN] bf16 (imp-folded): 10,485,760
  bf16*  w2t      = (bf16*)(ws + 10485760);      // [E][DOUT][DH] bf16: 2,097,152
  bf16*  xbuf     = (bf16*)(ws + 12582912);      // [8192][640] bf16: 10,485,760
  float* ew       = (float*)(ws + 23097344);     // [B][T][E]: 262,144
  float* counts   = (float*)(ws + 23359488);     // [T*E]: 32,768
  float* partials = (float*)(ws + 23392256);     // [32]: 128
  bf16*  Hbuf     = (bf16*)(ws + 23396352);      // [4][8192][1024] bf16: 67,108,864

  k_prep<<<dim3(6153), dim3(256), 0, stream>>>(h, ce, gn, ca, fi, W1, W2,
                                               w1t, w2t, xbuf, ew, out);
  k_g1<<<dim3(2048), dim3(256), 0, stream>>>(xbuf, w1t, b1, Hbuf, 0);
  k_g2<<<dim3(512), dim3(256), 0, stream>>>(Hbuf, w2t, b2, ew, out, 0);
  k_g1<<<dim3(2048), dim3(256), 0, stream>>>(xbuf, w1t, b1, Hbuf, 4);
  k_g2<<<dim3(512), dim3(256), 0, stream>>>(Hbuf, w2t, b2, ew, out, 4);
  k_counts<<<dim3(32), dim3(256), 0, stream>>>(ew, counts, partials);
  k_aux<<<dim3(1), dim3(256), 0, stream>>>(counts, partials, out);
}